// Round 12
// baseline (33.720 us; speedup 1.0000x reference)
//
#include <hip/hip_runtime.h>

// Deimv2LQE: out = scores + MLP(top4-softmax-stats(pred_corners))
// 262144 rows; per row 132 f32 (4 corners x 33 bins).
// R12 = R11 (wave-autonomous staging+corner, wave-split s_load MLP) with the
//   stat buffer ELIMINATED: stats embedded in each wave's own stage slice
//   (offsets [0,336) floats; MLP partials at [400,464)). Lockstep within a
//   wave guarantees all x-reads precede stat-writes -> no extra barrier.
//   LDS/block: 39168 -> 33792 B. Theory: usable LDS pool ~110-118 KB capped
//   residency at 2 blocks/CU; 33792*3 = 101 KB unlocks 3.

#define THREADS 256
#define ROWS 64

typedef float f32x4 __attribute__((ext_vector_type(4), aligned(16)));

__device__ __forceinline__ void sort4d(float& a, float& b, float& c, float& d) {
    float t;
    t = fmaxf(a, b); b = fminf(a, b); a = t;
    t = fmaxf(c, d); d = fminf(c, d); c = t;
    t = fmaxf(a, c); c = fminf(a, c); a = t;
    t = fmaxf(b, d); d = fminf(b, d); b = t;
    t = fmaxf(b, c); c = fminf(b, c); b = t;
}
__device__ __forceinline__ void ins4(float& a, float& b, float& c, float& d,
                                     float x) {
    float t;
    t = fmaxf(a, x); x = fminf(a, x); a = t;
    t = fmaxf(b, x); x = fminf(b, x); b = t;
    t = fmaxf(c, x); x = fminf(c, x); c = t;
    d = fmaxf(d, x);
}
__device__ __forceinline__ void merge4(float& a0, float& a1, float& a2,
                                       float& a3, float b0, float b1,
                                       float b2, float b3) {
    a0 = fmaxf(a0, b3);
    a1 = fmaxf(a1, b2);
    a2 = fmaxf(a2, b1);
    a3 = fmaxf(a3, b0);
    sort4d(a0, a1, a2, a3);
}

__global__ __launch_bounds__(THREADS, 4)
void lqe_kernel(const float* __restrict__ scores,
                const float* __restrict__ pc,
                const float* __restrict__ w1,
                const float* __restrict__ b1,
                const float* __restrict__ w2,
                const float* __restrict__ b2,
                float* __restrict__ out)
{
    // 4 wave slices of 2112 floats. Per slice:
    //   [0,336):   stats (16 rows x 21, odd stride)   -- written after x-reads
    //   [400,464): MLP partials (64 rows, this wave's j-slice)
    //   whole slice: staged corner data (read before stats overwrite head)
    __shared__ float smStage[ROWS * 132];   // 33792 B

    const int t  = threadIdx.x;
    const int wv = t >> 6;
    const int l  = t & 63;
    const long long rowBase = (long long)blockIdx.x * ROWS;

    float sc = 0.f;
    if (t < 64) sc = scores[rowBase + t];   // issued first, deep in queue

    // ---- wave-private stage: 528 contiguous f4 per wave, coalesced ----
    {
        const f32x4* __restrict__ src =
            (const f32x4*)(pc + rowBase * 132) + wv * 528;
        f32x4* dst = (f32x4*)smStage + wv * 528;
        #pragma unroll
        for (int i = 0; i < 8; ++i) dst[l + i * 64] = src[l + i * 64];
        if (l < 16) dst[512 + l] = src[512 + l];
    }

    // ---- corner task (wave-private, NO barrier): row = 16wv + (l>>2),
    //      corner = l&3; LDS base = wv*2112 + 33*l (odd stride, free) ----
    {
        const float* v = smStage + wv * 2112 + l * 33;
        float x[33];
        #pragma unroll
        for (int k = 0; k < 33; ++k) x[k] = v[k];

        float a0 = x[0],  a1 = x[1],  a2 = x[2],  a3 = x[3];
        float c0 = x[8],  c1 = x[9],  c2 = x[10], c3 = x[11];
        float d0 = x[16], d1 = x[17], d2 = x[18], d3 = x[19];
        float e0 = x[24], e1 = x[25], e2 = x[26], e3 = x[27];
        sort4d(a0, a1, a2, a3);
        sort4d(c0, c1, c2, c3);
        sort4d(d0, d1, d2, d3);
        sort4d(e0, e1, e2, e3);
        #pragma unroll
        for (int k = 0; k < 4; ++k) {
            ins4(a0, a1, a2, a3, x[4 + k]);
            ins4(c0, c1, c2, c3, x[12 + k]);
            ins4(d0, d1, d2, d3, x[20 + k]);
            ins4(e0, e1, e2, e3, x[28 + k]);
        }
        ins4(e0, e1, e2, e3, x[32]);
        merge4(a0, a1, a2, a3, c0, c1, c2, c3);
        merge4(d0, d1, d2, d3, e0, e1, e2, e3);
        merge4(a0, a1, a2, a3, d0, d1, d2, d3);
        const float t0 = a0, t1 = a1, t2 = a2, t3 = a3;

        float sa = 0.f, sb = 0.f, scc = 0.f, sd = 0.f;
        #pragma unroll
        for (int k = 0; k < 32; k += 4) {
            sa  += __expf(x[k + 0] - t0);
            sb  += __expf(x[k + 1] - t0);
            scc += __expf(x[k + 2] - t0);
            sd  += __expf(x[k + 3] - t0);
        }
        sa += __expf(x[32] - t0);
        const float inv = 1.0f / ((sa + sb) + (scc + sd));
        const float p0 = inv;
        const float p1 = __expf(t1 - t0) * inv;
        const float p2 = __expf(t2 - t0) * inv;
        const float p3 = __expf(t3 - t0) * inv;
        const float pm = 0.25f * (p0 + p1 + p2 + p3);

        // stats into OWN slice head [0,336). Lockstep: all lanes' x-reads
        // above are program-ordered before these writes -> WAR-safe in-wave.
        float* sd_ = smStage + wv * 2112 + (l >> 2) * 21 + (l & 3) * 5;
        sd_[0] = p0; sd_[1] = p1; sd_[2] = p2; sd_[3] = p3; sd_[4] = pm;
    }
    __syncthreads();   // all waves' stats visible

    // ---- MLP: wave wv -> hidden slice [16wv,16wv+16), lane = row ----
    {
        const int wvs = __builtin_amdgcn_readfirstlane(wv);  // scalar
        const float* __restrict__ w1s = w1 + wvs * 16;
        const float* __restrict__ w2s = w2 + wvs * 16;
        const float* __restrict__ b1s = b1 + wvs * 16;

        // row l's stats live in slice (l>>4) at (l&15)*21 + k  (2-way banks)
        float st[20];
        #pragma unroll
        for (int k = 0; k < 20; ++k)
            st[k] = smStage[(l >> 4) * 2112 + (l & 15) * 21 + k];

        float h[16];
        #pragma unroll
        for (int j = 0; j < 16; ++j) h[j] = b1s[j];
        #pragma unroll
        for (int k = 0; k < 20; ++k) {
            #pragma unroll
            for (int j = 0; j < 16; ++j)
                h[j] = fmaf(st[k], w1s[k * 64 + j], h[j]);
        }
        float acc0 = 0.f, acc1 = 0.f, acc2 = 0.f, acc3 = 0.f;
        #pragma unroll
        for (int j = 0; j < 16; j += 4) {
            acc0 = fmaf(fmaxf(h[j + 0], 0.f), w2s[j + 0], acc0);
            acc1 = fmaf(fmaxf(h[j + 1], 0.f), w2s[j + 1], acc1);
            acc2 = fmaf(fmaxf(h[j + 2], 0.f), w2s[j + 2], acc2);
            acc3 = fmaf(fmaxf(h[j + 3], 0.f), w2s[j + 3], acc3);
        }
        // partial for row l into OWN slice at [400,464) (disjoint from stats)
        smStage[wvs * 2112 + 400 + l] = (acc0 + acc1) + (acc2 + acc3);
    }
    __syncthreads();

    // ---- reduce 4 partials, add score, coalesced store ----
    if (t < 64) {
        const float r = (smStage[400 + t]        + smStage[2112 + 400 + t]) +
                        (smStage[4224 + 400 + t] + smStage[6336 + 400 + t]);
        out[rowBase + t] = sc + r + b2[0];
    }
}

extern "C" void kernel_launch(void* const* d_in, const int* in_sizes, int n_in,
                              void* d_out, int out_size, void* d_ws, size_t ws_size,
                              hipStream_t stream) {
    const float* scores = (const float*)d_in[0];
    const float* pc     = (const float*)d_in[1];
    const float* w1     = (const float*)d_in[2];
    const float* b1     = (const float*)d_in[3];
    const float* w2     = (const float*)d_in[4];
    const float* b2     = (const float*)d_in[5];
    float* out = (float*)d_out;

    const int rows = out_size;          // 262144
    const int blocks = rows / ROWS;     // 4096
    lqe_kernel<<<blocks, THREADS, 0, stream>>>(scores, pc, w1, b1, w2, b2, out);
}